// Round 7
// baseline (493.039 us; speedup 1.0000x reference)
//
#include <hip/hip_runtime.h>

#define D_DIM 4096
#define N_DIM 1024
#define NNZ_F 131072
#define K_F 4
#define NCHUNK 8               // one column-chunk per XCD
#define LPR 16                 // lanes per row (16B each -> 128 cols)
#define RPB 16                 // rows per block (16 rows x 16 lanes = 256 thr)
#define MAXE 1024              // LDS staging capacity for CSR entries per block
#define XS8 (N_DIM / 8)        // 128 uint4-slots (8 bf16) per row

#define T_TILES ((D_DIM / 64) * (N_DIM / 64))   // 1024 transpose tiles
#define GRID_P ((D_DIM / RPB) * NCHUNK)         // 2048 persistent blocks
#define BPC (GRID_P / NCHUNK)                   // 256 blocks per chunk

__device__ __forceinline__ unsigned short f2bf(float f) {
    union { float f; unsigned int u; } v; v.f = f;
    unsigned int r = v.u + 0x7fffu + ((v.u >> 16) & 1u);   // RNE, finite inputs
    return (unsigned short)(r >> 16);
}
__device__ __forceinline__ float bf_lo(unsigned int w) {
    return __uint_as_float(w << 16);
}
__device__ __forceinline__ float bf_hi(unsigned int w) {
    return __uint_as_float(w & 0xffff0000u);
}
__device__ __forceinline__ float bf2f(unsigned short h) {
    return __uint_as_float(((unsigned int)h) << 16);
}

// ---------- fused: transpose U [N,D] f32 -> UT [D,N] bf16  (+)  per-factor CSR count+scan
__global__ __launch_bounds__(1024) void fused_t_build_k(const float* __restrict__ in,
                                                        unsigned short* __restrict__ outb,
                                                        const int* __restrict__ rows,
                                                        int* __restrict__ row_ptr_g,
                                                        int* __restrict__ cursor_g) {
    __shared__ int s_cnt[4 * D_DIM];          // 64 KB: 4 sub-histograms OR transpose tile
    __shared__ int s_part[1024];
    const int tid = threadIdx.x;
    const int bid = blockIdx.x;

    if (bid < T_TILES) {
        // ---- transpose tile: 64x64, f32 in -> bf16 out ----
        float (*tile)[65] = (float (*)[65])s_cnt;
        const int gxi = bid & 63;            // tile along D
        const int gyi = bid >> 6;            // tile along N
        const int c0 = gxi * 64;             // offset in D
        const int r0 = gyi * 64;             // offset in N
        const int tx = tid & 63;
        const int ty = tid >> 6;             // 0..15
#pragma unroll
        for (int i = ty; i < 64; i += 16)
            tile[i][tx] = in[(size_t)(r0 + i) * D_DIM + c0 + tx];
        __syncthreads();
        const int px = (tid & 15) * 4;       // 4 n-locals per thread
        const int py = tid >> 4;             // 0..63 -> row of output tile
        ushort4 w;
        w.x = f2bf(tile[px + 0][py]);
        w.y = f2bf(tile[px + 1][py]);
        w.z = f2bf(tile[px + 2][py]);
        w.w = f2bf(tile[px + 3][py]);
        *(ushort4*)&outb[(size_t)(c0 + py) * N_DIM + r0 + px] = w;
        return;
    }

    // ---- CSR count + exclusive scan for factor f (one block per factor) ----
    const int f = bid - T_TILES;
    const int grp = (tid >> 8) & 3;          // 4 wave-groups, private histograms
#pragma unroll
    for (int k = 0; k < 16; ++k) s_cnt[tid + k * 1024] = 0;
    __syncthreads();

    int* h = s_cnt + grp * D_DIM;
    const int4* rp4 = (const int4*)(rows + (size_t)f * NNZ_F);
#pragma unroll 4
    for (int it = 0; it < NNZ_F / 4096; ++it) {      // 32 iters
        int4 r4 = rp4[(size_t)it * 1024 + tid];
        atomicAdd(&h[r4.x], 1);
        atomicAdd(&h[r4.y], 1);
        atomicAdd(&h[r4.z], 1);
        atomicAdd(&h[r4.w], 1);
    }
    __syncthreads();

    int c[4];
#pragma unroll
    for (int k = 0; k < 4; ++k)
        c[k] = s_cnt[tid * 4 + k] + s_cnt[D_DIM + tid * 4 + k]
             + s_cnt[2 * D_DIM + tid * 4 + k] + s_cnt[3 * D_DIM + tid * 4 + k];
    const int part = c[0] + c[1] + c[2] + c[3];
    s_part[tid] = part;
    __syncthreads();
    for (int off = 1; off < 1024; off <<= 1) {
        int v = (tid >= off) ? s_part[tid - off] : 0;
        __syncthreads();
        s_part[tid] += v;
        __syncthreads();
    }
    int excl = s_part[tid] - part;

    int* rp  = row_ptr_g + (size_t)f * (D_DIM + 1);
    int* cur = cursor_g + (size_t)f * D_DIM;
    int b = tid * 4;
#pragma unroll
    for (int k = 0; k < 4; ++k) {
        rp[b + k] = excl; cur[b + k] = excl; excl += c[k];
    }
    if (tid == 1023) rp[D_DIM] = NNZ_F;
}

// ---------- scatter all factors into CSR; block 0 zeroes the chunk barriers ----------
__global__ __launch_bounds__(1024) void scatter_all_k(const int* __restrict__ rows,
                                                      const int* __restrict__ cols,
                                                      const float* __restrict__ vals,
                                                      int* __restrict__ cursor,
                                                      int* __restrict__ csr_col,
                                                      float* __restrict__ csr_val,
                                                      int* __restrict__ arrive) {
    if (blockIdx.x == 0 && threadIdx.x < NCHUNK) arrive[threadIdx.x * 32] = 0;
    const int f = blockIdx.x >> 7;                        // 128 blocks per factor
    const size_t j = (size_t)(blockIdx.x & 127) * 1024 + threadIdx.x;
    const size_t base = (size_t)f * NNZ_F;
    int r = rows[base + j];
    int p = atomicAdd(&cursor[(size_t)f * D_DIM + r], 1);
    csr_col[base + p] = cols[base + j];
    csr_val[base + p] = vals[base + j];
}

// ---------- per-chunk barrier (256 blocks per chunk, monotone counter) ----------
__device__ __forceinline__ void chunk_barrier(int* arr, int target) {
    __syncthreads();
    if (threadIdx.x == 0) {
        __hip_atomic_fetch_add(arr, 1, __ATOMIC_RELEASE, __HIP_MEMORY_SCOPE_AGENT);
        while (__hip_atomic_load(arr, __ATOMIC_RELAXED, __HIP_MEMORY_SCOPE_AGENT) < target)
            __builtin_amdgcn_s_sleep(8);
        (void)__hip_atomic_load(arr, __ATOMIC_ACQUIRE, __HIP_MEMORY_SCOPE_AGENT);
    }
    __syncthreads();
}

// ---------- one spmm round (chunk-local, bf16 in AND out) ----------
__device__ __forceinline__ void spmm_phase(const int* __restrict__ row_ptr,
                                           const int* __restrict__ csr_col,
                                           const float* __restrict__ csr_val,
                                           const uint4* __restrict__ X,
                                           uint4* __restrict__ Y,
                                           int chunk, int rg,
                                           int* s_ptr, int* s_col, float* s_val) {
    const int tid  = threadIdx.x;
    const int r0   = rg * RPB;
    const int sub  = tid >> 4;                // row within group: 0..15
    const int lane = tid & 15;                // uint4 slot within chunk
    const int slot = chunk * LPR + lane;
    const int r    = r0 + sub;

    if (tid <= RPB) s_ptr[tid] = row_ptr[r0 + tid];
    __syncthreads();
    const int base  = s_ptr[0];
    const int total = s_ptr[RPB] - base;
    const int start = s_ptr[sub] - base;
    const int end_  = s_ptr[sub + 1] - base;

    float acc[8];
#pragma unroll
    for (int k = 0; k < 8; ++k) acc[k] = 0.f;

    for (int cb2 = 0; cb2 < total; cb2 += MAXE) {
        int cnt = total - cb2;
        if (cnt > MAXE) cnt = MAXE;
        for (int t = tid; t < cnt; t += 256) {
            s_col[t] = csr_col[base + cb2 + t];
            s_val[t] = csr_val[base + cb2 + t];
        }
        __syncthreads();
        int js = start > cb2 ? start : cb2;
        int je = end_ < cb2 + cnt ? end_ : cb2 + cnt;
        if (js < je) {
            int   jj = js - cb2;
            uint4 x  = X[(size_t)s_col[jj] * XS8 + slot];
            float v  = s_val[jj];
#pragma unroll 2
            for (int j = js + 1; j < je; ++j) {
                const int   jn = j - cb2;
                const uint4 xn = X[(size_t)s_col[jn] * XS8 + slot];
                const float vn = s_val[jn];
                acc[0] += v * bf_lo(x.x);
                acc[1] += v * bf_hi(x.x);
                acc[2] += v * bf_lo(x.y);
                acc[3] += v * bf_hi(x.y);
                acc[4] += v * bf_lo(x.z);
                acc[5] += v * bf_hi(x.z);
                acc[6] += v * bf_lo(x.w);
                acc[7] += v * bf_hi(x.w);
                x = xn; v = vn;
            }
            acc[0] += v * bf_lo(x.x);
            acc[1] += v * bf_hi(x.x);
            acc[2] += v * bf_lo(x.y);
            acc[3] += v * bf_hi(x.y);
            acc[4] += v * bf_lo(x.z);
            acc[5] += v * bf_hi(x.z);
            acc[6] += v * bf_lo(x.w);
            acc[7] += v * bf_hi(x.w);
        }
        __syncthreads();
    }

    uint4 o;
    o.x = (unsigned int)f2bf(acc[0]) | ((unsigned int)f2bf(acc[1]) << 16);
    o.y = (unsigned int)f2bf(acc[2]) | ((unsigned int)f2bf(acc[3]) << 16);
    o.z = (unsigned int)f2bf(acc[4]) | ((unsigned int)f2bf(acc[5]) << 16);
    o.w = (unsigned int)f2bf(acc[6]) | ((unsigned int)f2bf(acc[7]) << 16);
    Y[(size_t)r * XS8 + slot] = o;
}

// ---------- persistent fused chain: 4 spmm rounds + final transpose+bias ----------
// grid = 2048 blocks (8/CU via launch_bounds, co-resident). chunk = bid&7 (XCD-affine).
// ALL inter-phase dataflow is bf16 with identical layout and chunk-disjoint byte
// ranges (row*2048 + chunk*256 .. +256), so per-chunk barriers suffice. d_out is
// written ONLY by the final stage (no aliasing with any ping-pong buffer).
__global__ __launch_bounds__(256, 8) void fused_chain_k(const int* __restrict__ row_ptr_g,
                                                        const int* __restrict__ csr_col_g,
                                                        const float* __restrict__ csr_val_g,
                                                        uint4* bufA, uint4* bufB,
                                                        float* __restrict__ out,
                                                        const float* __restrict__ bias,
                                                        int* __restrict__ arrive) {
    __shared__ float smem[2 * MAXE + RPB + 2];
    int*   s_col = (int*)smem;
    float* s_val = smem + MAXE;
    int*   s_ptr = (int*)(smem + 2 * MAXE);

    const int chunk = blockIdx.x & (NCHUNK - 1);
    const int rg    = blockIdx.x >> 3;
    int* arr = arrive + chunk * 32;

    // f=3: A -> B
    spmm_phase(row_ptr_g + 3 * (D_DIM + 1), csr_col_g + 3 * (size_t)NNZ_F,
               csr_val_g + 3 * (size_t)NNZ_F, bufA, bufB, chunk, rg, s_ptr, s_col, s_val);
    chunk_barrier(arr, 1 * BPC);
    // f=2: B -> A
    spmm_phase(row_ptr_g + 2 * (D_DIM + 1), csr_col_g + 2 * (size_t)NNZ_F,
               csr_val_g + 2 * (size_t)NNZ_F, bufB, bufA, chunk, rg, s_ptr, s_col, s_val);
    chunk_barrier(arr, 2 * BPC);
    // f=1: A -> B
    spmm_phase(row_ptr_g + 1 * (D_DIM + 1), csr_col_g + 1 * (size_t)NNZ_F,
               csr_val_g + 1 * (size_t)NNZ_F, bufA, bufB, chunk, rg, s_ptr, s_col, s_val);
    chunk_barrier(arr, 3 * BPC);
    // f=0: B -> A (still bf16)
    spmm_phase(row_ptr_g + 0 * (D_DIM + 1), csr_col_g + 0 * (size_t)NNZ_F,
               csr_val_g + 0 * (size_t)NNZ_F, bufB, bufA, chunk, rg, s_ptr, s_col, s_val);
    chunk_barrier(arr, 4 * BPC);

    // transpose + bias: A bf16 [D, N] -> out f32 [N, D]; 2 chunk-local 32x32 tiles/block
    const unsigned short* srcb = (const unsigned short*)bufA;
    float (*tile)[33] = (float (*)[33])smem;
    const int tx = threadIdx.x & 31;
    const int ty = threadIdx.x >> 5;          // 0..7
#pragma unroll
    for (int t = 0; t < 2; ++t) {
        const int tile_id = rg * 2 + t;       // 0..511 within chunk
        const int d0 = (tile_id >> 2) * 32;
        const int n0 = chunk * 128 + (tile_id & 3) * 32;
        if (t) __syncthreads();
#pragma unroll
        for (int i = ty; i < 32; i += 8)
            tile[i][tx] = bf2f(srcb[(size_t)(d0 + i) * N_DIM + n0 + tx]);
        __syncthreads();
        const float b = bias[d0 + tx];
#pragma unroll
        for (int i = ty; i < 32; i += 8)
            out[(size_t)(n0 + i) * D_DIM + d0 + tx] = tile[tx][i] + b;
    }
}

extern "C" void kernel_launch(void* const* d_in, const int* in_sizes, int n_in,
                              void* d_out, int out_size, void* d_ws, size_t ws_size,
                              hipStream_t stream) {
    const float* U    = (const float*)d_in[0];
    const float* bias = (const float*)d_in[1];
    const float* vals = (const float*)d_in[2];
    const int*   rows = (const int*)d_in[3];
    const int*   cols = (const int*)d_in[4];
    float* out = (float*)d_out;

    char* ws = (char*)d_ws;
    size_t off = 0;
    char* bufA = ws;                   off += (size_t)D_DIM * N_DIM * 2;   // 8 MB bf16
    char* bufB = ws + off;             off += (size_t)D_DIM * N_DIM * 2;   // 8 MB bf16
    int* row_ptr = (int*)(ws + off);   off += (size_t)K_F * (D_DIM + 1) * 4;
    off = (off + 15) & ~(size_t)15;
    int* cursor  = (int*)(ws + off);   off += (size_t)K_F * D_DIM * 4;
    int*   csr_col = (int*)(ws + off); off += (size_t)K_F * NNZ_F * 4;
    float* csr_val = (float*)(ws + off); off += (size_t)K_F * NNZ_F * 4;
    off = (off + 127) & ~(size_t)127;
    int* arrive  = (int*)(ws + off);   off += (size_t)NCHUNK * 32 * 4;

    // K1: transpose U -> A (bf16) + CSR count/scan (4 blocks), fused
    fused_t_build_k<<<T_TILES + K_F, 1024, 0, stream>>>(
        U, (unsigned short*)bufA, rows, row_ptr, cursor);

    // K2: scatter all factors + zero chunk barriers
    scatter_all_k<<<K_F * (NNZ_F / 1024), 1024, 0, stream>>>(rows, cols, vals, cursor,
                                                             csr_col, csr_val, arrive);

    // K3: persistent fused chain (4 spmm + transpose+bias)
    fused_chain_k<<<GRID_P, 256, 0, stream>>>(row_ptr, csr_col, csr_val,
                                              (uint4*)bufA, (uint4*)bufB, out, bias, arrive);
}

// Round 8
// 113.658 us; speedup vs baseline: 4.3379x; 4.3379x over previous
//
#include <hip/hip_runtime.h>

#define D_DIM 4096
#define N_DIM 1024
#define NNZ_F 131072
#define K_F 4
#define NCHUNK 8               // one column-chunk per XCD
#define LPR 16                 // lanes per row (16B each -> 128 cols)
#define RPB 16                 // rows per block (16 rows x 16 lanes = 256 thr)
#define MAXE 1024              // LDS staging capacity for CSR entries per block
#define XS8 (N_DIM / 8)        // 128 uint4-slots (8 bf16) per row

#define T_TILES ((D_DIM / 64) * (N_DIM / 64))   // 1024 transpose tiles
#define TSTRIDE 132            // padded LDS stride for the 16x128 output tile

__device__ __forceinline__ unsigned short f2bf(float f) {
    union { float f; unsigned int u; } v; v.f = f;
    unsigned int r = v.u + 0x7fffu + ((v.u >> 16) & 1u);   // RNE, finite inputs
    return (unsigned short)(r >> 16);
}
__device__ __forceinline__ float bf_lo(unsigned int w) {
    return __uint_as_float(w << 16);
}
__device__ __forceinline__ float bf_hi(unsigned int w) {
    return __uint_as_float(w & 0xffff0000u);
}

// ---------- fused: transpose U [N,D] f32 -> UT [D,N] bf16  (+)  per-factor CSR count+scan
__global__ __launch_bounds__(1024) void fused_t_build_k(const float* __restrict__ in,
                                                        unsigned short* __restrict__ outb,
                                                        const int* __restrict__ rows,
                                                        int* __restrict__ row_ptr_g,
                                                        int* __restrict__ cursor_g) {
    __shared__ int s_cnt[4 * D_DIM];          // 64 KB: 4 sub-histograms OR transpose tile
    __shared__ int s_part[1024];
    const int tid = threadIdx.x;
    const int bid = blockIdx.x;

    if (bid < T_TILES) {
        // ---- transpose tile: 64x64, f32 in -> bf16 out ----
        float (*tile)[65] = (float (*)[65])s_cnt;
        const int gxi = bid & 63;            // tile along D
        const int gyi = bid >> 6;            // tile along N
        const int c0 = gxi * 64;             // offset in D
        const int r0 = gyi * 64;             // offset in N
        const int tx = tid & 63;
        const int ty = tid >> 6;             // 0..15
#pragma unroll
        for (int i = ty; i < 64; i += 16)
            tile[i][tx] = in[(size_t)(r0 + i) * D_DIM + c0 + tx];
        __syncthreads();
        const int px = (tid & 15) * 4;       // 4 n-locals per thread
        const int py = tid >> 4;             // 0..63 -> row of output tile
        ushort4 w;
        w.x = f2bf(tile[px + 0][py]);
        w.y = f2bf(tile[px + 1][py]);
        w.z = f2bf(tile[px + 2][py]);
        w.w = f2bf(tile[px + 3][py]);
        *(ushort4*)&outb[(size_t)(c0 + py) * N_DIM + r0 + px] = w;
        return;
    }

    // ---- CSR count + exclusive scan for factor f (one block per factor) ----
    const int f = bid - T_TILES;
    const int grp = (tid >> 8) & 3;          // 4 wave-groups, private histograms
#pragma unroll
    for (int k = 0; k < 16; ++k) s_cnt[tid + k * 1024] = 0;
    __syncthreads();

    int* h = s_cnt + grp * D_DIM;
    const int4* rp4 = (const int4*)(rows + (size_t)f * NNZ_F);
#pragma unroll 4
    for (int it = 0; it < NNZ_F / 4096; ++it) {      // 32 iters
        int4 r4 = rp4[(size_t)it * 1024 + tid];
        atomicAdd(&h[r4.x], 1);
        atomicAdd(&h[r4.y], 1);
        atomicAdd(&h[r4.z], 1);
        atomicAdd(&h[r4.w], 1);
    }
    __syncthreads();

    int c[4];
#pragma unroll
    for (int k = 0; k < 4; ++k)
        c[k] = s_cnt[tid * 4 + k] + s_cnt[D_DIM + tid * 4 + k]
             + s_cnt[2 * D_DIM + tid * 4 + k] + s_cnt[3 * D_DIM + tid * 4 + k];
    const int part = c[0] + c[1] + c[2] + c[3];
    s_part[tid] = part;
    __syncthreads();
    for (int off = 1; off < 1024; off <<= 1) {
        int v = (tid >= off) ? s_part[tid - off] : 0;
        __syncthreads();
        s_part[tid] += v;
        __syncthreads();
    }
    int excl = s_part[tid] - part;

    int* rp  = row_ptr_g + (size_t)f * (D_DIM + 1);
    int* cur = cursor_g + (size_t)f * D_DIM;
    int b = tid * 4;
#pragma unroll
    for (int k = 0; k < 4; ++k) {
        rp[b + k] = excl; cur[b + k] = excl; excl += c[k];
    }
    if (tid == 1023) rp[D_DIM] = NNZ_F;
}

// ---------- scatter all factors into CSR ----------
__global__ __launch_bounds__(1024) void scatter_all_k(const int* __restrict__ rows,
                                                      const int* __restrict__ cols,
                                                      const float* __restrict__ vals,
                                                      int* __restrict__ cursor,
                                                      int* __restrict__ csr_col,
                                                      float* __restrict__ csr_val) {
    const int f = blockIdx.x >> 7;                        // 128 blocks per factor
    const size_t j = (size_t)(blockIdx.x & 127) * 1024 + threadIdx.x;
    const size_t base = (size_t)f * NNZ_F;
    int r = rows[base + j];
    int p = atomicAdd(&cursor[(size_t)f * D_DIM + r], 1);
    csr_col[base + p] = cols[base + j];
    csr_val[base + p] = vals[base + j];
}

// ---------- chunked CSR spmm, bf16 input, 16B gathers ----------
// chunk = blockIdx & 7 -> XCD-affine; each XCD's L2 holds its 1MB bf16 column slice.
// 16 rows/block, 16 lanes/row, each lane: one uint4 (8 bf16 cols) per nnz.
// FINAL: LDS-transpose the block's 16(d) x 128(n) f32 tile, add bias, and write
// out[n][d] directly (kills the separate transpose kernel + f32 round-trip).
template <bool FINAL>
__global__ __launch_bounds__(256) void spmm_chunk_k(const int* __restrict__ row_ptr,
                                                    const int* __restrict__ csr_col,
                                                    const float* __restrict__ csr_val,
                                                    const uint4* __restrict__ X,
                                                    uint4* __restrict__ Y,
                                                    float* __restrict__ out,
                                                    const float* __restrict__ bias) {
    __shared__ float smem[16 * TSTRIDE];      // 2112 floats; also covers CSR staging
    int*   s_col = (int*)smem;                // [MAXE]
    float* s_val = smem + MAXE;               // [MAXE]
    int*   s_ptr = (int*)(smem + 2 * MAXE);   // [RPB+1]

    const int tid   = threadIdx.x;
    const int chunk = blockIdx.x & (NCHUNK - 1);
    const int rg    = blockIdx.x >> 3;
    const int r0    = rg * RPB;
    const int sub   = tid >> 4;               // row within group: 0..15
    const int lane  = tid & 15;               // uint4 slot within chunk
    const int slot  = chunk * LPR + lane;
    const int r     = r0 + sub;

    if (tid <= RPB) s_ptr[tid] = row_ptr[r0 + tid];
    __syncthreads();
    const int base  = s_ptr[0];
    const int total = s_ptr[RPB] - base;
    const int start = s_ptr[sub] - base;
    const int end_  = s_ptr[sub + 1] - base;

    float acc[8];
#pragma unroll
    for (int k = 0; k < 8; ++k) acc[k] = 0.f;

    for (int cb2 = 0; cb2 < total; cb2 += MAXE) {
        int cnt = total - cb2;
        if (cnt > MAXE) cnt = MAXE;
        for (int t = tid; t < cnt; t += 256) {
            s_col[t] = csr_col[base + cb2 + t];
            s_val[t] = csr_val[base + cb2 + t];
        }
        __syncthreads();
        int js = start > cb2 ? start : cb2;
        int je = end_ < cb2 + cnt ? end_ : cb2 + cnt;
        if (js < je) {
            int   jj = js - cb2;
            uint4 x  = X[(size_t)s_col[jj] * XS8 + slot];
            float v  = s_val[jj];
#pragma unroll 2
            for (int j = js + 1; j < je; ++j) {
                const int   jn = j - cb2;
                const uint4 xn = X[(size_t)s_col[jn] * XS8 + slot];
                const float vn = s_val[jn];
                acc[0] += v * bf_lo(x.x);
                acc[1] += v * bf_hi(x.x);
                acc[2] += v * bf_lo(x.y);
                acc[3] += v * bf_hi(x.y);
                acc[4] += v * bf_lo(x.z);
                acc[5] += v * bf_hi(x.z);
                acc[6] += v * bf_lo(x.w);
                acc[7] += v * bf_hi(x.w);
                x = xn; v = vn;
            }
            acc[0] += v * bf_lo(x.x);
            acc[1] += v * bf_hi(x.x);
            acc[2] += v * bf_lo(x.y);
            acc[3] += v * bf_hi(x.y);
            acc[4] += v * bf_lo(x.z);
            acc[5] += v * bf_hi(x.z);
            acc[6] += v * bf_lo(x.w);
            acc[7] += v * bf_hi(x.w);
        }
        __syncthreads();
    }

    if (!FINAL) {
        uint4 o;
        o.x = (unsigned int)f2bf(acc[0]) | ((unsigned int)f2bf(acc[1]) << 16);
        o.y = (unsigned int)f2bf(acc[2]) | ((unsigned int)f2bf(acc[3]) << 16);
        o.z = (unsigned int)f2bf(acc[4]) | ((unsigned int)f2bf(acc[5]) << 16);
        o.w = (unsigned int)f2bf(acc[6]) | ((unsigned int)f2bf(acc[7]) << 16);
        Y[(size_t)r * XS8 + slot] = o;
    } else {
        // stage 16(d) x 128(n) f32 tile in LDS (stride 132: 16B-aligned rows, 2-way banks)
        __syncthreads();                      // all s_ptr/s_col/s_val consumers done
        float* tile = smem;
        const int wbase = sub * TSTRIDE + lane * 8;
        *(float4*)&tile[wbase]     = make_float4(acc[0], acc[1], acc[2], acc[3]);
        *(float4*)&tile[wbase + 4] = make_float4(acc[4], acc[5], acc[6], acc[7]);
        __syncthreads();
        const int n0 = chunk * (N_DIM / NCHUNK);
#pragma unroll
        for (int f = tid; f < 512; f += 256) {
            const int n_loc = f >> 2;         // 0..127
            const int q     = f & 3;          // d quad within the 16-row tile
            float4 o;
            o.x = tile[(q * 4 + 0) * TSTRIDE + n_loc];
            o.y = tile[(q * 4 + 1) * TSTRIDE + n_loc];
            o.z = tile[(q * 4 + 2) * TSTRIDE + n_loc];
            o.w = tile[(q * 4 + 3) * TSTRIDE + n_loc];
            const float4 bv = *(const float4*)&bias[r0 + q * 4];
            o.x += bv.x; o.y += bv.y; o.z += bv.z; o.w += bv.w;
            *(float4*)&out[(size_t)(n0 + n_loc) * D_DIM + r0 + q * 4] = o;
        }
    }
}

extern "C" void kernel_launch(void* const* d_in, const int* in_sizes, int n_in,
                              void* d_out, int out_size, void* d_ws, size_t ws_size,
                              hipStream_t stream) {
    const float* U    = (const float*)d_in[0];
    const float* bias = (const float*)d_in[1];
    const float* vals = (const float*)d_in[2];
    const int*   rows = (const int*)d_in[3];
    const int*   cols = (const int*)d_in[4];
    float* out = (float*)d_out;

    char* ws = (char*)d_ws;
    size_t off = 0;
    char* bufA = ws;                   off += (size_t)D_DIM * N_DIM * 2;   // 8 MB bf16
    char* bufB = ws + off;             off += (size_t)D_DIM * N_DIM * 2;   // 8 MB bf16
    int* row_ptr = (int*)(ws + off);   off += (size_t)K_F * (D_DIM + 1) * 4;
    off = (off + 15) & ~(size_t)15;
    int* cursor  = (int*)(ws + off);   off += (size_t)K_F * D_DIM * 4;
    int*   csr_col = (int*)(ws + off); off += (size_t)K_F * NNZ_F * 4;
    float* csr_val = (float*)(ws + off); off += (size_t)K_F * NNZ_F * 4;

    const int grid_spmm = (D_DIM / RPB) * NCHUNK;   // 256 * 8 = 2048 blocks

    // K1: transpose U -> A (bf16) + CSR count/scan (4 blocks), fused
    fused_t_build_k<<<T_TILES + K_F, 1024, 0, stream>>>(
        U, (unsigned short*)bufA, rows, row_ptr, cursor);

    // K2: scatter all factors
    scatter_all_k<<<K_F * (NNZ_F / 1024), 1024, 0, stream>>>(rows, cols, vals, cursor,
                                                             csr_col, csr_val);

    // K3: factor 3, A -> B
    spmm_chunk_k<false><<<grid_spmm, 256, 0, stream>>>(
        row_ptr + 3 * (D_DIM + 1), csr_col + 3 * (size_t)NNZ_F, csr_val + 3 * (size_t)NNZ_F,
        (const uint4*)bufA, (uint4*)bufB, nullptr, nullptr);
    // K4: factor 2, B -> A
    spmm_chunk_k<false><<<grid_spmm, 256, 0, stream>>>(
        row_ptr + 2 * (D_DIM + 1), csr_col + 2 * (size_t)NNZ_F, csr_val + 2 * (size_t)NNZ_F,
        (const uint4*)bufB, (uint4*)bufA, nullptr, nullptr);
    // K5: factor 1, A -> B
    spmm_chunk_k<false><<<grid_spmm, 256, 0, stream>>>(
        row_ptr + 1 * (D_DIM + 1), csr_col + 1 * (size_t)NNZ_F, csr_val + 1 * (size_t)NNZ_F,
        (const uint4*)bufA, (uint4*)bufB, nullptr, nullptr);
    // K6: factor 0, B -> out (transposed + bias, fused)
    spmm_chunk_k<true><<<grid_spmm, 256, 0, stream>>>(
        row_ptr + 0 * (D_DIM + 1), csr_col + 0 * (size_t)NNZ_F, csr_val + 0 * (size_t)NNZ_F,
        (const uint4*)bufB, nullptr, out, bias);
}